// Round 5
// baseline (936.347 us; speedup 1.0000x reference)
//
#include <hip/hip_runtime.h>

// TGN data-collect, single-kernel formulation.
// D = 172 f32 = 43 float4 per row. All work is gathers + trivial elementwise.
// Phase ordering is enforced by block-ID ranges (CDNA dispatches blocks roughly
// in order): tiny dm segments first, then node gathers (L3 working set =
// node_feats+memory = 137.6 MB, fits 256 MB L3), then edge gathers last so
// their ~1 GB stream evicts the node tables only after they're done.
// All outputs use non-temporal stores (zero reuse -> don't pollute L3).

typedef float f32x4 __attribute__((ext_vector_type(4)));

static constexpr unsigned D4 = 43;

// segment block counts (256 threads/block, exact — no remainders)
static constexpr unsigned DM1_B = 81920u / 256u;           // 320
static constexpr unsigned DM2_B = 1638400u / 256u;         // 6400
static constexpr unsigned S1_B  = (4096u * D4) / 256u;     // 688
static constexpr unsigned N1_B  = (81920u * D4) / 256u;    // 13760
static constexpr unsigned N2_B  = (1638400u * D4) / 256u;  // 275200
static constexpr unsigned E1_B  = (81920u * D4) / 256u;    // 13760
static constexpr unsigned E2_B  = (1638400u * D4) / 256u;  // 275200
static constexpr unsigned TOT_B = DM1_B + DM2_B + S1_B + N1_B + N2_B + E1_B + E2_B; // 585328

__global__ __launch_bounds__(256) void tgn_all(
    const f32x4* __restrict__ nf,   // node_feats   [100000*43]
    const f32x4* __restrict__ mem,  // memory       [100000*43]
    const f32x4* __restrict__ ef,   // edge_feats   [1000000*43]
    const float* __restrict__ ts,   // timestamps   [4096]
    const float* __restrict__ et1,  // edge_times1  [81920]
    const float* __restrict__ et2,  // edge_times2  [1638400]
    const int*   __restrict__ srcn, // source_nodes [4096]
    const int*   __restrict__ nb1,  // neighbors1   [81920]
    const int*   __restrict__ ei1,  // edge_idxs1   [81920]
    const int*   __restrict__ nb2,  // neighbors2   [1638400]
    const int*   __restrict__ ei2,  // edge_idxs2   [1638400]
    f32x4* __restrict__ src1,       // [4096*43]
    f32x4* __restrict__ nf1o,       // [81920*43]
    f32x4* __restrict__ ef1o,       // [81920*43]
    float* __restrict__ dl1,        // [81920]
    float* __restrict__ mk1,        // [81920]
    f32x4* __restrict__ sf2,        // [81920*43]
    f32x4* __restrict__ nf2o,       // [1638400*43]
    f32x4* __restrict__ ef2o,       // [1638400*43]
    float* __restrict__ dl2,        // [1638400]
    float* __restrict__ mk2)        // [1638400]
{
    unsigned b = blockIdx.x;
    unsigned t = threadIdx.x;

    if (b < DM1_B) {                                   // deltas1 / mask1
        unsigned i = b * 256u + t;
        __builtin_nontemporal_store(ts[i / 20u] - et1[i], dl1 + i);
        __builtin_nontemporal_store((nb1[i] == 0) ? 1.0f : 0.0f, mk1 + i);
        return;
    }
    b -= DM1_B;
    if (b < DM2_B) {                                   // deltas2 / mask2
        unsigned i = b * 256u + t;
        __builtin_nontemporal_store(ts[i / 400u] - et2[i], dl2 + i);
        __builtin_nontemporal_store((nb2[i] == 0) ? 1.0f : 0.0f, mk2 + i);
        return;
    }
    b -= DM2_B;
    if (b < S1_B) {                                    // src_feats1 = nm[srcn]
        unsigned i = b * 256u + t;
        unsigned row = i / D4, col = i - row * D4;
        unsigned s = (unsigned)srcn[row] * D4 + col;
        __builtin_nontemporal_store(nf[s] + mem[s], src1 + i);
        return;
    }
    b -= S1_B;
    if (b < N1_B) {                                    // neigh_feats1 + src_feats2
        unsigned i = b * 256u + t;
        unsigned row = i / D4, col = i - row * D4;
        unsigned s = (unsigned)nb1[row] * D4 + col;
        f32x4 v = nf[s] + mem[s];
        __builtin_nontemporal_store(v, nf1o + i);
        __builtin_nontemporal_store(v, sf2 + i);
        return;
    }
    b -= N1_B;
    if (b < N2_B) {                                    // neigh_feats2 (big node gather)
        unsigned i = b * 256u + t;
        unsigned row = i / D4, col = i - row * D4;
        unsigned s = (unsigned)nb2[row] * D4 + col;
        __builtin_nontemporal_store(nf[s] + mem[s], nf2o + i);
        return;
    }
    b -= N2_B;
    if (b < E1_B) {                                    // edge_f1
        unsigned i = b * 256u + t;
        unsigned row = i / D4, col = i - row * D4;
        __builtin_nontemporal_store(ef[(unsigned)ei1[row] * D4 + col], ef1o + i);
        return;
    }
    b -= E1_B;
    {                                                  // edge_f2 (big edge gather, last)
        unsigned i = b * 256u + t;
        unsigned row = i / D4, col = i - row * D4;
        __builtin_nontemporal_store(ef[(unsigned)ei2[row] * D4 + col], ef2o + i);
    }
}

extern "C" void kernel_launch(void* const* d_in, const int* in_sizes, int n_in,
                              void* d_out, int out_size, void* d_ws, size_t ws_size,
                              hipStream_t stream) {
    const f32x4* nf  = (const f32x4*)d_in[0];
    const f32x4* ef  = (const f32x4*)d_in[1];
    const f32x4* mem = (const f32x4*)d_in[2];
    const float* ts  = (const float*)d_in[3];
    const float* et1 = (const float*)d_in[4];
    const float* et2 = (const float*)d_in[5];
    const int* srcn  = (const int*)d_in[6];
    const int* nb1   = (const int*)d_in[7];
    const int* ei1   = (const int*)d_in[8];
    const int* nb2   = (const int*)d_in[9];
    const int* ei2   = (const int*)d_in[10];

    constexpr unsigned B = 4096, K = 20, Dd = 172;
    constexpr unsigned BK = B * K;              // 81920

    float* out = (float*)d_out;
    size_t o = 0;
    float* src1 = out + o;  o += (size_t)B * Dd;        // src_feats1
    float* nf1  = out + o;  o += (size_t)BK * Dd;       // neigh_feats1
    float* ef1  = out + o;  o += (size_t)BK * Dd;       // edge_f1
    float* dl1  = out + o;  o += (size_t)BK;            // deltas1
    float* mk1  = out + o;  o += (size_t)BK;            // mask1
    float* sf2  = out + o;  o += (size_t)BK * Dd;       // src_feats2
    float* nf2  = out + o;  o += (size_t)BK * K * Dd;   // neigh_feats2
    float* ef2  = out + o;  o += (size_t)BK * K * Dd;   // edge_f2
    float* dl2  = out + o;  o += (size_t)BK * K;        // deltas2
    float* mk2  = out + o;  o += (size_t)BK * K;        // mask2

    tgn_all<<<TOT_B, 256, 0, stream>>>(
        nf, mem, ef, ts, et1, et2, srcn, nb1, ei1, nb2, ei2,
        (f32x4*)src1, (f32x4*)nf1, (f32x4*)ef1, dl1, mk1,
        (f32x4*)sf2, (f32x4*)nf2, (f32x4*)ef2, dl2, mk2);
}